// Round 17
// baseline (117.075 us; speedup 1.0000x reference)
//
#include <hip/hip_runtime.h>
#include <hip/hip_bf16.h>

typedef unsigned short ushort_t;
typedef unsigned int uint_t;
typedef __attribute__((ext_vector_type(8))) short short8;
typedef __attribute__((ext_vector_type(4))) float f32x4;
typedef __attribute__((ext_vector_type(2))) uint_t uint2_t;

#define FOLD 128
// exp(COEFF*x^2) = 2^(-(x*S)^2);  S = sqrt(0.5/ln2)/DELTA, DELTA = 30/63
#define S_CONST 1.78357580f
#define DS_CONST 0.84932180f   /* DELTA * S_CONST = sqrt(0.5/ln2) */

__device__ __forceinline__ uint_t pkbf(float a, float b) {
    __hip_bfloat162 h2 = __float22bfloat162_rn(float2{a, b});
    uint_t u;
    __builtin_memcpy(&u, &h2, sizeof(u));
    return u;
}

// ---- AoS position packing: one 64B line per protein atom (all 5 channels),
//      one 16B record per ligand atom.
__global__ __launch_bounds__(256) void pack_pos(
    const float* __restrict__ p0, const float* __restrict__ p1,
    const float* __restrict__ p2, const float* __restrict__ p3,
    const float* __restrict__ p4, const float* __restrict__ lig,
    float* __restrict__ P5, float* __restrict__ L4, int NP, int NL)
{
    int i = blockIdx.x * 256 + threadIdx.x;
    if (i < NP) {
        float r[16];
        const float* ps0 = p0 + 3 * i; const float* ps1 = p1 + 3 * i;
        const float* ps2 = p2 + 3 * i; const float* ps3 = p3 + 3 * i;
        const float* ps4 = p4 + 3 * i;
        r[0]=ps0[0]; r[1]=ps0[1]; r[2]=ps0[2];
        r[3]=ps1[0]; r[4]=ps1[1]; r[5]=ps1[2];
        r[6]=ps2[0]; r[7]=ps2[1]; r[8]=ps2[2];
        r[9]=ps3[0]; r[10]=ps3[1]; r[11]=ps3[2];
        r[12]=ps4[0]; r[13]=ps4[1]; r[14]=ps4[2];
        r[15]=0.f;
        #pragma unroll
        for (int k = 0; k < 4; ++k)
            *reinterpret_cast<f32x4*>(&P5[(size_t)i * 16 + k * 4]) =
                *reinterpret_cast<f32x4*>(&r[k * 4]);
    } else if (i < NP + NL) {
        int j = i - NP;
        f32x4 v = {lig[3 * j], lig[3 * j + 1], lig[3 * j + 2], 0.f};
        *reinterpret_cast<f32x4*>(&L4[(size_t)j * 4]) = v;
    }
}

// ---- Pure-gather distance pass: D[e][c] = |lig[src[e]] - pc[dst[e]]|.
// No competing write stream -> positions stay L2/L3-resident. Regular (non-NT)
// stores so D stays L3-hot for the streaming consumer.
__global__ __launch_bounds__(256) void dist_k(
    const float* __restrict__ P5, const float* __restrict__ L4,
    const int* __restrict__ src, const int* __restrict__ dst,
    float* __restrict__ D, int E)
{
    int e = blockIdx.x * 256 + threadIdx.x;
    if (e >= E) return;
    int s = src[e], d2 = dst[e];
    f32x4 lv = *reinterpret_cast<const f32x4*>(&L4[(size_t)s * 4]);
    f32x4 r0 = *reinterpret_cast<const f32x4*>(&P5[(size_t)d2 * 16]);
    f32x4 r1 = *reinterpret_cast<const f32x4*>(&P5[(size_t)d2 * 16 + 4]);
    f32x4 r2 = *reinterpret_cast<const f32x4*>(&P5[(size_t)d2 * 16 + 8]);
    f32x4 r3 = *reinterpret_cast<const f32x4*>(&P5[(size_t)d2 * 16 + 12]);
    float px[5] = {r0[0], r0[3], r1[2], r2[1], r3[0]};
    float py[5] = {r0[1], r1[0], r1[3], r2[2], r3[1]};
    float pz[5] = {r0[2], r1[1], r2[0], r2[3], r3[2]};
    float dv[5];
    #pragma unroll
    for (int c = 0; c < 5; ++c) {
        float dx = lv[0] - px[c], dy = lv[1] - py[c], dz = lv[2] - pz[c];
        dv[c] = sqrtf(dx * dx + dy * dy + dz * dz);
    }
    f32x4 v4 = {dv[0], dv[1], dv[2], dv[3]};
    *reinterpret_cast<f32x4*>(&D[(size_t)e * 5]) = v4;   // 4B-aligned dwordx4
    D[(size_t)e * 5 + 4] = dv[4];
}

#define NWAVES 8
#define W1_OFF 0        /* 20480 dw: W1 bf16 fragment-packed */
#define W2_OFF 20480    /*  8192 dw: W2 bf16 fragment-packed */
#define B1_OFF 28672
#define B2_OFF 28800
#define H_OFF  28928    /*  8 waves x 1024 dw h-scratch */
#define LDS_DW 37120

// ---- Streaming main kernel: R13 compute core, distances from dense D ----
__global__ __launch_bounds__(512) void fused_d(
    const float* __restrict__ D,
    const float* __restrict__ W1, const float* __restrict__ W2,
    const float* __restrict__ b1, const float* __restrict__ b2,
    float* __restrict__ out, int E)
{
    extern __shared__ uint_t smem[];
    uint_t* W1L = smem + W1_OFF;
    uint_t* W2L = smem + W2_OFF;
    const float* b1L = (const float*)(smem + B1_OFF);
    const float* b2L = (const float*)(smem + B2_OFF);

    const int t = threadIdx.x;
    const int w = t >> 6;
    const int l = t & 63;
    const int eL = l & 15, g = l >> 4;
    uint_t* hw = smem + H_OFF + (w << 10);

    // ---- Stage W1/W2 bf16 fragments + biases into LDS, once ----
    for (int idx = t; idx < 20480; idx += 512) {
        int jj = idx & 3, l2 = (idx >> 2) & 63, nt = (idx >> 8) & 7, ks = idx >> 11;
        int row = ks * 32 + ((l2 >> 4) << 3) + 2 * jj;
        int col = nt * 16 + (l2 & 15);
        W1L[idx] = pkbf(W1[row * FOLD + col], W1[(row + 1) * FOLD + col]);
    }
    for (int idx = t; idx < 8192; idx += 512) {
        int jj = idx & 3, l2 = (idx >> 2) & 63, nt = (idx >> 8) & 7, ks = idx >> 11;
        int row = ks * 32 + ((l2 >> 4) << 3) + 2 * jj;
        int col = nt * 16 + (l2 & 15);
        W2L[idx] = pkbf(W2[row * FOLD + col], W2[(row + 1) * FOLD + col]);
    }
    if (t < 128) ((float*)(smem + B1_OFF))[t] = b1[t];
    else if (t < 256) ((float*)(smem + B2_OFF))[t - 128] = b2[t - 128];
    __syncthreads();   // the ONLY block barrier

    const int NT = (E + 31) >> 5;
    const int stride = gridDim.x * NWAVES;
    int wt = blockIdx.x * NWAVES + w;
    if (wt >= NT) return;

    const float gbase = (float)(8 * g) * DS_CONST;

    // ---- Prologue: load first tile's distances (dense, computable address) ----
    f32x4 d03[2]; float d4v[2];
    #pragma unroll
    for (int eh = 0; eh < 2; ++eh) {
        int e = wt * 32 + eh * 16 + eL; if (e >= E) e = E - 1;
        d03[eh] = *reinterpret_cast<const f32x4*>(&D[(size_t)e * 5]);
        d4v[eh] = D[(size_t)e * 5 + 4];
    }

    while (true) {
        const int wt2 = wt + stride;
        const bool more = (wt2 < NT);

        // ---- Issue next tile's distance loads (streaming prefetch) ----
        f32x4 nd03[2]; float nd4[2];
        if (more) {
            #pragma unroll
            for (int eh = 0; eh < 2; ++eh) {
                int e = wt2 * 32 + eh * 16 + eL; if (e >= E) e = E - 1;
                nd03[eh] = *reinterpret_cast<const f32x4*>(&D[(size_t)e * 5]);
                nd4[eh] = D[(size_t)e * 5 + 4];
            }
        }

        // ---- u00 directly (no shuffles) ----
        float u00[5][2];
        #pragma unroll
        for (int eh = 0; eh < 2; ++eh) {
            #pragma unroll
            for (int c = 0; c < 4; ++c)
                u00[c][eh] = __builtin_fmaf(d03[eh][c], S_CONST, -gbase);
            u00[4][eh] = __builtin_fmaf(d4v[eh], S_CONST, -gbase);
        }

        // ---- RBF expansion into register B-fragments ----
        short8 a[2][10];
        #pragma unroll
        for (int ks = 0; ks < 10; ++ks) {
            const int c = ks >> 1;
            #pragma unroll
            for (int eh = 0; eh < 2; ++eh) {
                uint_t dwv[4];
                #pragma unroll
                for (int jj = 0; jj < 4; ++jj) {
                    float k0 = (float)((ks & 1) * 32 + 2 * jj) * DS_CONST;
                    float k1 = (float)((ks & 1) * 32 + 2 * jj + 1) * DS_CONST;
                    float ua = u00[c][eh] - k0;
                    float ub = u00[c][eh] - k1;
                    float va = __builtin_amdgcn_exp2f(-(ua * ua));
                    float vb = __builtin_amdgcn_exp2f(-(ub * ub));
                    dwv[jj] = pkbf(va, vb);
                }
                __builtin_memcpy(&a[eh][ks], dwv, 16);
            }
        }

        // ---- GEMM1 ----
        f32x4 acc1[8][2];
        #pragma unroll
        for (int nt = 0; nt < 8; ++nt)
            #pragma unroll
            for (int eh = 0; eh < 2; ++eh) acc1[nt][eh] = f32x4{0.f, 0.f, 0.f, 0.f};
        #pragma unroll
        for (int ks = 0; ks < 10; ++ks) {
            #pragma unroll
            for (int nt = 0; nt < 8; ++nt) {
                const short8 wf = *reinterpret_cast<const short8*>(&W1L[((ks * 8 + nt) * 64 + l) * 4]);
                acc1[nt][0] = __builtin_amdgcn_mfma_f32_16x16x32_bf16(wf, a[0][ks], acc1[nt][0], 0, 0, 0);
                acc1[nt][1] = __builtin_amdgcn_mfma_f32_16x16x32_bf16(wf, a[1][ks], acc1[nt][1], 0, 0, 0);
            }
        }

        // ---- Per edge-half: h round-trip, GEMM2, store ----
        const int swzE = (eL & 7) << 3;
        #pragma unroll
        for (int eh = 0; eh < 2; ++eh) {
            #pragma unroll
            for (int nt = 0; nt < 8; ++nt) {
                f32x4 bv = *reinterpret_cast<const f32x4*>(&b1L[nt * 16 + g * 4]);
                float v0 = fmaxf(acc1[nt][eh][0] + bv[0], 0.f);
                float v1 = fmaxf(acc1[nt][eh][1] + bv[1], 0.f);
                float v2 = fmaxf(acc1[nt][eh][2] + bv[2], 0.f);
                float v3 = fmaxf(acc1[nt][eh][3] + bv[3], 0.f);
                uint2_t pv;
                pv[0] = pkbf(v0, v1);
                pv[1] = pkbf(v2, v3);
                *reinterpret_cast<uint2_t*>(&hw[eL * 64 + ((nt * 8 + g * 2) ^ swzE)]) = pv;
            }
            f32x4 acc2[8];
            #pragma unroll
            for (int nt = 0; nt < 8; ++nt) acc2[nt] = f32x4{0.f, 0.f, 0.f, 0.f};
            #pragma unroll
            for (int ks2 = 0; ks2 < 4; ++ks2) {
                const short8 hf = *reinterpret_cast<const short8*>(&hw[eL * 64 + ((ks2 * 16 + g * 4) ^ swzE)]);
                #pragma unroll
                for (int nt = 0; nt < 8; ++nt) {
                    const short8 wf2 = *reinterpret_cast<const short8*>(&W2L[((ks2 * 8 + nt) * 64 + l) * 4]);
                    acc2[nt] = __builtin_amdgcn_mfma_f32_16x16x32_bf16(wf2, hf, acc2[nt], 0, 0, 0);
                }
            }
            int e = wt * 32 + eh * 16 + eL;
            if (e < E) {
                #pragma unroll
                for (int nt = 0; nt < 8; ++nt) {
                    f32x4 bv2 = *reinterpret_cast<const f32x4*>(&b2L[nt * 16 + g * 4]);
                    f32x4 v = acc2[nt] + bv2;
                    __builtin_nontemporal_store(v,
                        reinterpret_cast<f32x4*>(&out[(size_t)e * FOLD + nt * 16 + g * 4]));
                }
            }
            asm volatile("s_waitcnt lgkmcnt(0)" ::: "memory");
        }

        if (!more) break;
        wt = wt2;
        #pragma unroll
        for (int eh = 0; eh < 2; ++eh) { d03[eh] = nd03[eh]; d4v[eh] = nd4[eh]; }
    }
}

// ---- Fallback (R13 path): gather in-loop, used only if ws too small ----
__global__ __launch_bounds__(512) void fused_g(
    const float* __restrict__ lig,
    const float* __restrict__ p0, const float* __restrict__ p1,
    const float* __restrict__ p2, const float* __restrict__ p3,
    const float* __restrict__ p4,
    const float* __restrict__ W1, const float* __restrict__ W2,
    const float* __restrict__ b1, const float* __restrict__ b2,
    const int* __restrict__ src, const int* __restrict__ dst,
    float* __restrict__ out, int E)
{
    extern __shared__ uint_t smem[];
    uint_t* W1L = smem + W1_OFF;
    uint_t* W2L = smem + W2_OFF;
    const float* b1L = (const float*)(smem + B1_OFF);
    const float* b2L = (const float*)(smem + B2_OFF);

    const int t = threadIdx.x;
    const int w = t >> 6;
    const int l = t & 63;
    const int eL = l & 15, g = l >> 4;
    uint_t* hw = smem + H_OFF + (w << 10);

    for (int idx = t; idx < 20480; idx += 512) {
        int jj = idx & 3, l2 = (idx >> 2) & 63, nt = (idx >> 8) & 7, ks = idx >> 11;
        int row = ks * 32 + ((l2 >> 4) << 3) + 2 * jj;
        int col = nt * 16 + (l2 & 15);
        W1L[idx] = pkbf(W1[row * FOLD + col], W1[(row + 1) * FOLD + col]);
    }
    for (int idx = t; idx < 8192; idx += 512) {
        int jj = idx & 3, l2 = (idx >> 2) & 63, nt = (idx >> 8) & 7, ks = idx >> 11;
        int row = ks * 32 + ((l2 >> 4) << 3) + 2 * jj;
        int col = nt * 16 + (l2 & 15);
        W2L[idx] = pkbf(W2[row * FOLD + col], W2[(row + 1) * FOLD + col]);
    }
    if (t < 128) ((float*)(smem + B1_OFF))[t] = b1[t];
    else if (t < 256) ((float*)(smem + B2_OFF))[t - 128] = b2[t - 128];
    __syncthreads();

    const int NT = (E + 31) >> 5;
    const int stride = gridDim.x * NWAVES;
    int wt = blockIdx.x * NWAVES + w;
    if (wt >= NT) return;

    const float* GP = (g == 0) ? p0 : (g == 1) ? p1 : (g == 2) ? p2 : p3;
    const bool g0 = (g == 0);
    const float gbase = (float)(8 * g) * DS_CONST;

    float Ax[2], Ay[2], Az[2], Px[2], Py[2], Pz[2], Qx[2], Qy[2], Qz[2];
    #pragma unroll
    for (int eh = 0; eh < 2; ++eh) {
        int e = wt * 32 + eh * 16 + eL; if (e >= E) e = E - 1;
        int s = src[e], d2 = dst[e];
        Ax[eh] = lig[3 * s]; Ay[eh] = lig[3 * s + 1]; Az[eh] = lig[3 * s + 2];
        Px[eh] = GP[3 * d2]; Py[eh] = GP[3 * d2 + 1]; Pz[eh] = GP[3 * d2 + 2];
        if (g0) { Qx[eh] = p4[3 * d2]; Qy[eh] = p4[3 * d2 + 1]; Qz[eh] = p4[3 * d2 + 2]; }
    }
    int sB[2], dB[2];
    if (wt + stride < NT) {
        #pragma unroll
        for (int eh = 0; eh < 2; ++eh) {
            int e = (wt + stride) * 32 + eh * 16 + eL; if (e >= E) e = E - 1;
            sB[eh] = src[e]; dB[eh] = dst[e];
        }
    }

    while (true) {
        const int wt2 = wt + stride;
        const bool more = (wt2 < NT);

        float Bx[2], By[2], Bz[2], Rx[2], Ry[2], Rz[2], Sx[2], Sy[2], Sz[2];
        if (more) {
            #pragma unroll
            for (int eh = 0; eh < 2; ++eh) {
                Bx[eh] = lig[3 * sB[eh]]; By[eh] = lig[3 * sB[eh] + 1]; Bz[eh] = lig[3 * sB[eh] + 2];
                Rx[eh] = GP[3 * dB[eh]]; Ry[eh] = GP[3 * dB[eh] + 1]; Rz[eh] = GP[3 * dB[eh] + 2];
                if (g0) { Sx[eh] = p4[3 * dB[eh]]; Sy[eh] = p4[3 * dB[eh] + 1]; Sz[eh] = p4[3 * dB[eh] + 2]; }
            }
        }
        int sB2[2], dB2[2];
        if (wt2 + stride < NT) {
            #pragma unroll
            for (int eh = 0; eh < 2; ++eh) {
                int e = (wt2 + stride) * 32 + eh * 16 + eL; if (e >= E) e = E - 1;
                sB2[eh] = src[e]; dB2[eh] = dst[e];
            }
        }

        float u00[5][2];
        #pragma unroll
        for (int eh = 0; eh < 2; ++eh) {
            float dx = Ax[eh] - Px[eh], dy = Ay[eh] - Py[eh], dz = Az[eh] - Pz[eh];
            float dm = sqrtf(dx * dx + dy * dy + dz * dz);
            float d4 = 0.f;
            if (g0) {
                float ex = Ax[eh] - Qx[eh], ey = Ay[eh] - Qy[eh], ez = Az[eh] - Qz[eh];
                d4 = sqrtf(ex * ex + ey * ey + ez * ez);
            }
            #pragma unroll
            for (int c = 0; c < 4; ++c)
                u00[c][eh] = __builtin_fmaf(__shfl(dm, c * 16 + eL), S_CONST, -gbase);
            u00[4][eh] = __builtin_fmaf(__shfl(d4, eL), S_CONST, -gbase);
        }

        short8 a[2][10];
        #pragma unroll
        for (int ks = 0; ks < 10; ++ks) {
            const int c = ks >> 1;
            #pragma unroll
            for (int eh = 0; eh < 2; ++eh) {
                uint_t dwv[4];
                #pragma unroll
                for (int jj = 0; jj < 4; ++jj) {
                    float k0 = (float)((ks & 1) * 32 + 2 * jj) * DS_CONST;
                    float k1 = (float)((ks & 1) * 32 + 2 * jj + 1) * DS_CONST;
                    float ua = u00[c][eh] - k0;
                    float ub = u00[c][eh] - k1;
                    float va = __builtin_amdgcn_exp2f(-(ua * ua));
                    float vb = __builtin_amdgcn_exp2f(-(ub * ub));
                    dwv[jj] = pkbf(va, vb);
                }
                __builtin_memcpy(&a[eh][ks], dwv, 16);
            }
        }

        f32x4 acc1[8][2];
        #pragma unroll
        for (int nt = 0; nt < 8; ++nt)
            #pragma unroll
            for (int eh = 0; eh < 2; ++eh) acc1[nt][eh] = f32x4{0.f, 0.f, 0.f, 0.f};
        #pragma unroll
        for (int ks = 0; ks < 10; ++ks) {
            #pragma unroll
            for (int nt = 0; nt < 8; ++nt) {
                const short8 wf = *reinterpret_cast<const short8*>(&W1L[((ks * 8 + nt) * 64 + l) * 4]);
                acc1[nt][0] = __builtin_amdgcn_mfma_f32_16x16x32_bf16(wf, a[0][ks], acc1[nt][0], 0, 0, 0);
                acc1[nt][1] = __builtin_amdgcn_mfma_f32_16x16x32_bf16(wf, a[1][ks], acc1[nt][1], 0, 0, 0);
            }
        }

        const int swzE = (eL & 7) << 3;
        #pragma unroll
        for (int eh = 0; eh < 2; ++eh) {
            #pragma unroll
            for (int nt = 0; nt < 8; ++nt) {
                f32x4 bv = *reinterpret_cast<const f32x4*>(&b1L[nt * 16 + g * 4]);
                float v0 = fmaxf(acc1[nt][eh][0] + bv[0], 0.f);
                float v1 = fmaxf(acc1[nt][eh][1] + bv[1], 0.f);
                float v2 = fmaxf(acc1[nt][eh][2] + bv[2], 0.f);
                float v3 = fmaxf(acc1[nt][eh][3] + bv[3], 0.f);
                uint2_t pv;
                pv[0] = pkbf(v0, v1);
                pv[1] = pkbf(v2, v3);
                *reinterpret_cast<uint2_t*>(&hw[eL * 64 + ((nt * 8 + g * 2) ^ swzE)]) = pv;
            }
            f32x4 acc2[8];
            #pragma unroll
            for (int nt = 0; nt < 8; ++nt) acc2[nt] = f32x4{0.f, 0.f, 0.f, 0.f};
            #pragma unroll
            for (int ks2 = 0; ks2 < 4; ++ks2) {
                const short8 hf = *reinterpret_cast<const short8*>(&hw[eL * 64 + ((ks2 * 16 + g * 4) ^ swzE)]);
                #pragma unroll
                for (int nt = 0; nt < 8; ++nt) {
                    const short8 wf2 = *reinterpret_cast<const short8*>(&W2L[((ks2 * 8 + nt) * 64 + l) * 4]);
                    acc2[nt] = __builtin_amdgcn_mfma_f32_16x16x32_bf16(wf2, hf, acc2[nt], 0, 0, 0);
                }
            }
            int e = wt * 32 + eh * 16 + eL;
            if (e < E) {
                #pragma unroll
                for (int nt = 0; nt < 8; ++nt) {
                    f32x4 bv2 = *reinterpret_cast<const f32x4*>(&b2L[nt * 16 + g * 4]);
                    f32x4 v = acc2[nt] + bv2;
                    __builtin_nontemporal_store(v,
                        reinterpret_cast<f32x4*>(&out[(size_t)e * FOLD + nt * 16 + g * 4]));
                }
            }
            asm volatile("s_waitcnt lgkmcnt(0)" ::: "memory");
        }

        if (!more) break;
        wt = wt2;
        #pragma unroll
        for (int eh = 0; eh < 2; ++eh) {
            Ax[eh] = Bx[eh]; Ay[eh] = By[eh]; Az[eh] = Bz[eh];
            Px[eh] = Rx[eh]; Py[eh] = Ry[eh]; Pz[eh] = Rz[eh];
            if (g0) { Qx[eh] = Sx[eh]; Qy[eh] = Sy[eh]; Qz[eh] = Sz[eh]; }
            sB[eh] = sB2[eh]; dB[eh] = dB2[eh];
        }
    }
}

extern "C" void kernel_launch(void* const* d_in, const int* in_sizes, int n_in,
                              void* d_out, int out_size, void* d_ws, size_t ws_size,
                              hipStream_t stream) {
    const float* lig = (const float*)d_in[0];
    const float* p0  = (const float*)d_in[1];
    const float* p1  = (const float*)d_in[2];
    const float* p2  = (const float*)d_in[3];
    const float* p3  = (const float*)d_in[4];
    const float* p4  = (const float*)d_in[5];
    const float* W1  = (const float*)d_in[6];
    const float* b1  = (const float*)d_in[7];
    const float* W2  = (const float*)d_in[8];
    const float* b2  = (const float*)d_in[9];
    const int* src   = (const int*)d_in[10];
    const int* dst   = (const int*)d_in[11];
    float* out = (float*)d_out;
    const int E  = in_sizes[10];
    const int NL = in_sizes[0] / 3;
    const int NP = in_sizes[1] / 3;

    const size_t need = ((size_t)NP * 16 + (size_t)NL * 4 + (size_t)E * 5) * sizeof(float);

    hipFuncSetAttribute(reinterpret_cast<const void*>(fused_d),
                        hipFuncAttributeMaxDynamicSharedMemorySize, LDS_DW * 4);
    hipFuncSetAttribute(reinterpret_cast<const void*>(fused_g),
                        hipFuncAttributeMaxDynamicSharedMemorySize, LDS_DW * 4);

    if (ws_size >= need) {
        float* P5 = (float*)d_ws;
        float* L4 = P5 + (size_t)NP * 16;
        float* D  = L4 + (size_t)NL * 4;
        pack_pos<<<(NP + NL + 255) / 256, 256, 0, stream>>>(p0, p1, p2, p3, p4, lig,
                                                            P5, L4, NP, NL);
        dist_k<<<(E + 255) / 256, 256, 0, stream>>>(P5, L4, src, dst, D, E);
        fused_d<<<256, 512, LDS_DW * 4, stream>>>(D, W1, W2, b1, b2, out, E);
    } else {
        fused_g<<<256, 512, LDS_DW * 4, stream>>>(lig, p0, p1, p2, p3, p4,
                                                  W1, W2, b1, b2, src, dst, out, E);
    }
}

// Round 18
// 105.325 us; speedup vs baseline: 1.1116x; 1.1116x over previous
//
#include <hip/hip_runtime.h>
#include <hip/hip_bf16.h>

typedef unsigned short ushort_t;
typedef unsigned int uint_t;
typedef __attribute__((ext_vector_type(8))) short short8;
typedef __attribute__((ext_vector_type(4))) float f32x4;
typedef __attribute__((ext_vector_type(2))) uint_t uint2_t;

#define FOLD 128
// exp(COEFF*x^2) = 2^(-(x*S)^2);  S = sqrt(0.5/ln2)/DELTA, DELTA = 30/63
#define S_CONST 1.78357580f
#define DS_CONST 0.84932180f   /* DELTA * S_CONST = sqrt(0.5/ln2) */

__device__ __forceinline__ uint_t pkbf(float a, float b) {
    // dword = bf16(b)<<16 | bf16(a), RNE via v_cvt_pk_bf16_f32
    __hip_bfloat162 h2 = __float22bfloat162_rn(float2{a, b});
    uint_t u;
    __builtin_memcpy(&u, &h2, sizeof(u));
    return u;
}

#define NWAVES 8
// dword offsets in dynamic LDS (total 37120 dwords = 145 KB)
#define W1_OFF 0        /* 20480 dw: W1 bf16 fragment-packed */
#define W2_OFF 20480    /*  8192 dw: W2 bf16 fragment-packed */
#define B1_OFF 28672    /*   128 dw fp32 */
#define B2_OFF 28800    /*   128 dw fp32 */
#define H_OFF  28928    /*  8 waves x 1024 dw h-scratch */
#define LDS_DW 37120

// R13 kernel verbatim, ONE change: plain stores instead of non-temporal.
// (NT entered in R8 bundled with softbar+late-consume and was never isolated.
//  Theory: NT's no-allocate path flushes 64B partial segments instead of
//  letting L2 accumulate full lines from the 16 disjoint 64B-per-wave-store
//  pattern -> ~2x write cost. Plain stores let L2 merge.)
__global__ __launch_bounds__(512) void fused(
    const float* __restrict__ lig,
    const float* __restrict__ p0, const float* __restrict__ p1,
    const float* __restrict__ p2, const float* __restrict__ p3,
    const float* __restrict__ p4,
    const float* __restrict__ W1, const float* __restrict__ W2,
    const float* __restrict__ b1, const float* __restrict__ b2,
    const int* __restrict__ src, const int* __restrict__ dst,
    float* __restrict__ out, int E)
{
    extern __shared__ uint_t smem[];
    uint_t* W1L = smem + W1_OFF;
    uint_t* W2L = smem + W2_OFF;
    const float* b1L = (const float*)(smem + B1_OFF);
    const float* b2L = (const float*)(smem + B2_OFF);

    const int t = threadIdx.x;
    const int w = t >> 6;
    const int l = t & 63;
    const int eL = l & 15, g = l >> 4;
    uint_t* hw = smem + H_OFF + (w << 10);   // 4 KB private scratch per wave

    // ---- Stage W1/W2 (bf16 fragment order) + biases into LDS, once ----
    for (int idx = t; idx < 20480; idx += 512) {
        int jj = idx & 3, l2 = (idx >> 2) & 63, nt = (idx >> 8) & 7, ks = idx >> 11;
        int row = ks * 32 + ((l2 >> 4) << 3) + 2 * jj;
        int col = nt * 16 + (l2 & 15);
        W1L[idx] = pkbf(W1[row * FOLD + col], W1[(row + 1) * FOLD + col]);
    }
    for (int idx = t; idx < 8192; idx += 512) {
        int jj = idx & 3, l2 = (idx >> 2) & 63, nt = (idx >> 8) & 7, ks = idx >> 11;
        int row = ks * 32 + ((l2 >> 4) << 3) + 2 * jj;
        int col = nt * 16 + (l2 & 15);
        W2L[idx] = pkbf(W2[row * FOLD + col], W2[(row + 1) * FOLD + col]);
    }
    if (t < 128) ((float*)(smem + B1_OFF))[t] = b1[t];
    else if (t < 256) ((float*)(smem + B2_OFF))[t - 128] = b2[t - 128];
    __syncthreads();   // the ONLY block barrier

    const int NT = (E + 31) >> 5;
    const int stride = gridDim.x * NWAVES;
    int wt = blockIdx.x * NWAVES + w;
    if (wt >= NT) return;

    // lane's gather duty: channel g (0..3) via GP; lanes g==0 also do channel 4 (p4)
    const float* GP = (g == 0) ? p0 : (g == 1) ? p1 : (g == 2) ? p2 : p3;
    const bool g0 = (g == 0);
    const float gbase = (float)(8 * g) * DS_CONST;

    // ---- Prologue: idx + pos loads for first tile (both edge halves) ----
    float Ax[2], Ay[2], Az[2], Px[2], Py[2], Pz[2], Qx[2], Qy[2], Qz[2];
    {
        #pragma unroll
        for (int eh = 0; eh < 2; ++eh) {
            int e = wt * 32 + eh * 16 + eL; if (e >= E) e = E - 1;
            int s = src[e], d2 = dst[e];
            Ax[eh] = lig[3 * s]; Ay[eh] = lig[3 * s + 1]; Az[eh] = lig[3 * s + 2];
            Px[eh] = GP[3 * d2]; Py[eh] = GP[3 * d2 + 1]; Pz[eh] = GP[3 * d2 + 2];
            if (g0) { Qx[eh] = p4[3 * d2]; Qy[eh] = p4[3 * d2 + 1]; Qz[eh] = p4[3 * d2 + 2]; }
        }
    }

    while (true) {
        const int wt2 = wt + stride;
        const bool more = (wt2 < NT);

        // ---- Issue next tile's src/dst loads ----
        int sB[2], dB[2];
        if (more) {
            #pragma unroll
            for (int eh = 0; eh < 2; ++eh) {
                int e = wt2 * 32 + eh * 16 + eL; if (e >= E) e = E - 1;
                sB[eh] = src[e]; dB[eh] = dst[e];
            }
        }

        // ---- Distances + cross-lane redistribution (wave-local shuffles) ----
        float u00[5][2];
        #pragma unroll
        for (int eh = 0; eh < 2; ++eh) {
            float dx = Ax[eh] - Px[eh], dy = Ay[eh] - Py[eh], dz = Az[eh] - Pz[eh];
            float dm = sqrtf(dx * dx + dy * dy + dz * dz);   // channel g of edge eL
            float d4 = 0.f;
            if (g0) {
                float ex = Ax[eh] - Qx[eh], ey = Ay[eh] - Qy[eh], ez = Az[eh] - Qz[eh];
                d4 = sqrtf(ex * ex + ey * ey + ez * ez);
            }
            #pragma unroll
            for (int c = 0; c < 4; ++c)
                u00[c][eh] = __builtin_fmaf(__shfl(dm, c * 16 + eL), S_CONST, -gbase);
            u00[4][eh] = __builtin_fmaf(__shfl(d4, eL), S_CONST, -gbase);
        }

        // ---- RBF expansion into register B-fragments a[eh][ks] ----
        short8 a[2][10];
        #pragma unroll
        for (int ks = 0; ks < 10; ++ks) {
            const int c = ks >> 1;
            #pragma unroll
            for (int eh = 0; eh < 2; ++eh) {
                uint_t dwv[4];
                #pragma unroll
                for (int jj = 0; jj < 4; ++jj) {
                    float k0 = (float)((ks & 1) * 32 + 2 * jj) * DS_CONST;
                    float k1 = (float)((ks & 1) * 32 + 2 * jj + 1) * DS_CONST;
                    float ua = u00[c][eh] - k0;
                    float ub = u00[c][eh] - k1;
                    float va = __builtin_amdgcn_exp2f(-(ua * ua));
                    float vb = __builtin_amdgcn_exp2f(-(ub * ub));
                    dwv[jj] = pkbf(va, vb);
                }
                __builtin_memcpy(&a[eh][ks], dwv, 16);
            }
        }

        // ---- Issue next tile's position loads (indices arrived during exp) ----
        float Bx[2], By[2], Bz[2], Rx[2], Ry[2], Rz[2], Sx[2], Sy[2], Sz[2];
        if (more) {
            #pragma unroll
            for (int eh = 0; eh < 2; ++eh) {
                Bx[eh] = lig[3 * sB[eh]]; By[eh] = lig[3 * sB[eh] + 1]; Bz[eh] = lig[3 * sB[eh] + 2];
                Rx[eh] = GP[3 * dB[eh]]; Ry[eh] = GP[3 * dB[eh] + 1]; Rz[eh] = GP[3 * dB[eh] + 2];
                if (g0) { Sx[eh] = p4[3 * dB[eh]]; Sy[eh] = p4[3 * dB[eh] + 1]; Sz[eh] = p4[3 * dB[eh] + 2]; }
            }
        }

        // ---- GEMM1: acc1[nt][eh] = (W1^T-chunk)·attr; each W-frag read once ----
        f32x4 acc1[8][2];
        #pragma unroll
        for (int nt = 0; nt < 8; ++nt)
            #pragma unroll
            for (int eh = 0; eh < 2; ++eh) acc1[nt][eh] = f32x4{0.f, 0.f, 0.f, 0.f};
        #pragma unroll
        for (int ks = 0; ks < 10; ++ks) {
            #pragma unroll
            for (int nt = 0; nt < 8; ++nt) {
                const short8 wf = *reinterpret_cast<const short8*>(&W1L[((ks * 8 + nt) * 64 + l) * 4]);
                acc1[nt][0] = __builtin_amdgcn_mfma_f32_16x16x32_bf16(wf, a[0][ks], acc1[nt][0], 0, 0, 0);
                acc1[nt][1] = __builtin_amdgcn_mfma_f32_16x16x32_bf16(wf, a[1][ks], acc1[nt][1], 0, 0, 0);
            }
        }

        // ---- Per edge-half: h round-trip through private scratch, GEMM2, store ----
        const int swzE = (eL & 7) << 3;
        #pragma unroll
        for (int eh = 0; eh < 2; ++eh) {
            // bias + relu + pack h (lane: 4 ch of edge eL per nt)
            #pragma unroll
            for (int nt = 0; nt < 8; ++nt) {
                f32x4 bv = *reinterpret_cast<const f32x4*>(&b1L[nt * 16 + g * 4]);
                float v0 = fmaxf(acc1[nt][eh][0] + bv[0], 0.f);
                float v1 = fmaxf(acc1[nt][eh][1] + bv[1], 0.f);
                float v2 = fmaxf(acc1[nt][eh][2] + bv[2], 0.f);
                float v3 = fmaxf(acc1[nt][eh][3] + bv[3], 0.f);
                uint2_t pv;
                pv[0] = pkbf(v0, v1);
                pv[1] = pkbf(v2, v3);
                *reinterpret_cast<uint2_t*>(&hw[eL * 64 + ((nt * 8 + g * 2) ^ swzE)]) = pv;
            }
            // GEMM2 from scratch (wave-local; compiler orders ds ops via lgkmcnt)
            f32x4 acc2[8];
            #pragma unroll
            for (int nt = 0; nt < 8; ++nt) acc2[nt] = f32x4{0.f, 0.f, 0.f, 0.f};
            #pragma unroll
            for (int ks2 = 0; ks2 < 4; ++ks2) {
                const short8 hf = *reinterpret_cast<const short8*>(&hw[eL * 64 + ((ks2 * 16 + g * 4) ^ swzE)]);
                #pragma unroll
                for (int nt = 0; nt < 8; ++nt) {
                    const short8 wf2 = *reinterpret_cast<const short8*>(&W2L[((ks2 * 8 + nt) * 64 + l) * 4]);
                    acc2[nt] = __builtin_amdgcn_mfma_f32_16x16x32_bf16(wf2, hf, acc2[nt], 0, 0, 0);
                }
            }
            // stores — PLAIN (L2-allocating): let L2 merge the 64B halves into
            // full lines before writeback.
            int e = wt * 32 + eh * 16 + eL;
            if (e < E) {
                #pragma unroll
                for (int nt = 0; nt < 8; ++nt) {
                    f32x4 bv2 = *reinterpret_cast<const f32x4*>(&b2L[nt * 16 + g * 4]);
                    f32x4 v = acc2[nt] + bv2;
                    *reinterpret_cast<f32x4*>(&out[(size_t)e * FOLD + nt * 16 + g * 4]) = v;
                }
            }
            // drain this half's LDS ops before overwriting scratch
            asm volatile("s_waitcnt lgkmcnt(0)" ::: "memory");
        }

        if (!more) break;
        wt = wt2;
        #pragma unroll
        for (int eh = 0; eh < 2; ++eh) {
            Ax[eh] = Bx[eh]; Ay[eh] = By[eh]; Az[eh] = Bz[eh];
            Px[eh] = Rx[eh]; Py[eh] = Ry[eh]; Pz[eh] = Rz[eh];
            if (g0) { Qx[eh] = Sx[eh]; Qy[eh] = Sy[eh]; Qz[eh] = Sz[eh]; }
        }
    }
}

extern "C" void kernel_launch(void* const* d_in, const int* in_sizes, int n_in,
                              void* d_out, int out_size, void* d_ws, size_t ws_size,
                              hipStream_t stream) {
    const float* lig = (const float*)d_in[0];
    const float* p0  = (const float*)d_in[1];
    const float* p1  = (const float*)d_in[2];
    const float* p2  = (const float*)d_in[3];
    const float* p3  = (const float*)d_in[4];
    const float* p4  = (const float*)d_in[5];
    const float* W1  = (const float*)d_in[6];
    const float* b1  = (const float*)d_in[7];
    const float* W2  = (const float*)d_in[8];
    const float* b2  = (const float*)d_in[9];
    const int* src   = (const int*)d_in[10];
    const int* dst   = (const int*)d_in[11];
    float* out = (float*)d_out;
    const int E = in_sizes[10];

    hipFuncSetAttribute(reinterpret_cast<const void*>(fused),
                        hipFuncAttributeMaxDynamicSharedMemorySize, LDS_DW * 4);

    int nblk = 256;   // 1 block/CU (145 KB LDS); 8 autonomous waves per block
    fused<<<nblk, 512, LDS_DW * 4, stream>>>(lig, p0, p1, p2, p3, p4, W1, W2,
                                             b1, b2, src, dst, out, E);
}